// Round 10
// baseline (275.890 us; speedup 1.0000x reference)
//
#include <hip/hip_runtime.h>

#define NN 100000
#define KK 16
#define DD 128
#define DEE 32
#define DTT 32
#define C1 192        // D + DE + DT
#define BN 32         // nodes per block
#define AB 200        // aggb row stride in shorts; ≡4 words mod 32 banks -> 2-way (free)
#define A2B 264       // a2b row stride in shorts; ≡4 words mod 32 banks -> 2-way (free)
#define GRID (NN / BN)

// ws layout
#define W1T_SH 24576                     // per layer: 24*128*8
#define WLAYER_SH 57344                  // shorts per layer (W1T + W2T)
#define WTOT_SH (2 * WLAYER_SH)          // 229376 B total
#define TMP_OFF_B 229376                 // bf16 layer-0 out
#define TMP_B (NN * DD * 2)              // 25.6 MB
#define FBF_OFF_B (TMP_OFF_B + TMP_B)    // bf16 features
#define FBF_B (NN * DD * 2)              // 25.6 MB

#define FBF_BLOCKS (NN * DD / 4 / 256)   // 12500
#define PREP_BLOCKS (WTOT_SH / 256)      // 448

typedef __attribute__((ext_vector_type(8))) short bfrag;    // 8 bf16 = 4 VGPR (MFMA A/B)
typedef __attribute__((ext_vector_type(4))) float f32x4;    // MFMA C/D + NT-loadable vec4
typedef __attribute__((ext_vector_type(4))) short short4v;  // 8-byte chunk

__device__ __forceinline__ short f2bf(float x) {  // RNE f32 -> bf16 bits
  unsigned u = __builtin_bit_cast(unsigned, x);
  unsigned r = u + 0x7fffu + ((u >> 16) & 1u);
  return (short)(r >> 16);
}
__device__ __forceinline__ float bf2f(short s) {
  unsigned u = ((unsigned)(unsigned short)s) << 16;
  return __builtin_bit_cast(float, u);
}

// ---- merged prep: features f32->bf16 table, then W1/W2 -> bf16 fragment-major ----
__global__ void prep_all(const float* __restrict__ f, short* __restrict__ fo,
                         const float* __restrict__ W1, const float* __restrict__ W2,
                         short* __restrict__ wo) {
  const int b = blockIdx.x;
  if (b < FBF_BLOCKS) {
    const size_t i = ((size_t)b * 256 + threadIdx.x) * 4;
    const f32x4 v = __builtin_nontemporal_load(reinterpret_cast<const f32x4*>(f + i));
    short4v s; s[0] = f2bf(v[0]); s[1] = f2bf(v[1]); s[2] = f2bf(v[2]); s[3] = f2bf(v[3]);
    *reinterpret_cast<short4v*>(fo + i) = s;
    return;
  }
  const int t = (b - FBF_BLOCKS) * 256 + threadIdx.x;
  const int l = t / WLAYER_SH;
  const int r = t % WLAYER_SH;
  float v;
  if (r < W1T_SH) {
    const int kg = r >> 10, col = (r >> 3) & 127, j = r & 7;
    v = W1[(size_t)l * C1 * DD + (size_t)(kg * 8 + j) * DD + col];
  } else {
    const int r2 = r - W1T_SH;
    const int kg = r2 >> 10, col = (r2 >> 3) & 127, j = r2 & 7;
    v = W2[(size_t)l * 2 * DD * DD + (size_t)(kg * 8 + j) * DD + col];
  }
  wo[t] = f2bf(v);
}

// ---- fused TGN layer (R9 structure + fused stream∥gather phase 0) ----
template<bool OUTBF>
__global__ __launch_bounds__(256, 5) void tgn(
    const short* __restrict__ prevb,  // bf16 gather table == GEMM2-A rows
    const float* __restrict__ edge,   // [N, K, DE]
    const float* __restrict__ timef,  // [N, K, DT]
    const short* __restrict__ wT,     // [W1T | W2T] bf16 fragment-major
    const float* __restrict__ b1g,    // [128]
    const float* __restrict__ b2g,    // [128]
    const int* __restrict__ idxg,     // [N, K]
    void* __restrict__ out_)          // [N, D]
{
  __shared__ short aggb[BN][AB];   // [nbr_sum | e_sum | t_sum], K=192
  __shared__ short a2b[BN][A2B];   // [prev | h], K=256

  const int t  = threadIdx.x;
  const int n0 = blockIdx.x * BN;   // NN % BN == 0

  // phase 0a: stage this block's own prev rows -> a2b[:, 0:128]
  {
    const int d4 = (t & 31) * 4;
    for (int nl = t >> 5; nl < BN; nl += 8) {
      const short4v o = *reinterpret_cast<const short4v*>(prevb + (size_t)(n0 + nl) * DD + d4);
      *reinterpret_cast<short4v*>(&a2b[nl][d4]) = o;
    }
  }

  // phase 0: FUSED stream (HBM, NT) + gather (L3) so both memory classes are
  // in flight per wave throughout.
  {
    // stream role: node nls = t>>3, cols c4..c4+3 of e/t sums
    const int c4  = (t & 7) * 4;
    const int nls = t >> 3;  // 0..31
    const f32x4* ep = reinterpret_cast<const f32x4*>(edge  + (size_t)(n0 + nls) * KK * DEE + c4);
    const f32x4* tp = reinterpret_cast<const f32x4*>(timef + (size_t)(n0 + nls) * KK * DTT + c4);
    float e0=0,e1=0,e2=0,e3=0, s0=0,s1=0,s2=0,s3=0;

    // gather role: cols d4..d4+3, rows nr, nr+8 (pass 0) and nr+16, nr+24 (pass 1)
    const int d4 = (t & 31) * 4;
    const int nr = t >> 5;  // 0..7

    #pragma unroll
    for (int p = 0; p < 2; ++p) {
      const int nlA = nr + p * 16;
      const int nlB = nlA + 8;
      const int4* ipA = reinterpret_cast<const int4*>(idxg + (size_t)(n0 + nlA) * KK);
      const int4* ipB = reinterpret_cast<const int4*>(idxg + (size_t)(n0 + nlB) * KK);
      const int4 a0i = ipA[0], a1i = ipA[1], a2i = ipA[2], a3i = ipA[3];
      const int4 b0i = ipB[0], b1i = ipB[1], b2i = ipB[2], b3i = ipB[3];
      const int rowsA[16] = {a0i.x, a0i.y, a0i.z, a0i.w, a1i.x, a1i.y, a1i.z, a1i.w,
                             a2i.x, a2i.y, a2i.z, a2i.w, a3i.x, a3i.y, a3i.z, a3i.w};
      const int rowsB[16] = {b0i.x, b0i.y, b0i.z, b0i.w, b1i.x, b1i.y, b1i.z, b1i.w,
                             b2i.x, b2i.y, b2i.z, b2i.w, b3i.x, b3i.y, b3i.z, b3i.w};
      float aA0=0, aA1=0, aA2=0, aA3=0;
      float aB0=0, aB1=0, aB2=0, aB3=0;
      #pragma unroll
      for (int j = 0; j < 16; ++j) {
        // 2 gather loads (L3 path)
        const short4v vA = *reinterpret_cast<const short4v*>(prevb + (size_t)rowsA[j] * DD + d4);
        const short4v vB = *reinterpret_cast<const short4v*>(prevb + (size_t)rowsB[j] * DD + d4);
        // 1 stream pair (HBM path) every other iteration: 8 per pass, 16 total
        if ((j & 1) == 0) {
          const int sj = p * 8 + (j >> 1);
          const f32x4 ev = __builtin_nontemporal_load(ep + sj * (DEE / 4));
          const f32x4 tv = __builtin_nontemporal_load(tp + sj * (DTT / 4));
          e0 += ev[0]; e1 += ev[1]; e2 += ev[2]; e3 += ev[3];
          s0 += tv[0]; s1 += tv[1]; s2 += tv[2]; s3 += tv[3];
        }
        aA0 += bf2f(vA[0]); aA1 += bf2f(vA[1]); aA2 += bf2f(vA[2]); aA3 += bf2f(vA[3]);
        aB0 += bf2f(vB[0]); aB1 += bf2f(vB[1]); aB2 += bf2f(vB[2]); aB3 += bf2f(vB[3]);
      }
      short4v oA; oA[0]=f2bf(aA0); oA[1]=f2bf(aA1); oA[2]=f2bf(aA2); oA[3]=f2bf(aA3);
      short4v oB; oB[0]=f2bf(aB0); oB[1]=f2bf(aB1); oB[2]=f2bf(aB2); oB[3]=f2bf(aB3);
      *reinterpret_cast<short4v*>(&aggb[nlA][d4]) = oA;
      *reinterpret_cast<short4v*>(&aggb[nlB][d4]) = oB;
    }

    short4v eo; eo[0]=f2bf(e0); eo[1]=f2bf(e1); eo[2]=f2bf(e2); eo[3]=f2bf(e3);
    short4v so; so[0]=f2bf(s0); so[1]=f2bf(s1); so[2]=f2bf(s2); so[3]=f2bf(s3);
    *reinterpret_cast<short4v*>(&aggb[nls][DD + c4])       = eo;
    *reinterpret_cast<short4v*>(&aggb[nls][DD + DEE + c4]) = so;
  }
  __syncthreads();  // aggb + a2b[:,0:128] ready

  const int lane = t & 63;
  const int wv   = t >> 6;
  const int lr   = lane & 15;
  const int lg   = lane >> 4;
  const int n0w  = wv * 32;

  // ---- GEMM1: h = relu(aggb @ W1 + b1) -> a2b[:, 128:256] ----
  {
    f32x4 acc[2][2];
    #pragma unroll
    for (int nt = 0; nt < 2; ++nt) {
      const float bv = b1g[n0w + nt * 16 + lr];
      acc[0][nt] = (f32x4){bv, bv, bv, bv};
      acc[1][nt] = (f32x4){bv, bv, bv, bv};
    }
    #pragma unroll
    for (int ks = 0; ks < 6; ++ks) {
      const bfrag a0 = *reinterpret_cast<const bfrag*>(&aggb[lr][ks * 32 + lg * 8]);
      const bfrag a1 = *reinterpret_cast<const bfrag*>(&aggb[16 + lr][ks * 32 + lg * 8]);
      const short* wp = wT + ((size_t)((ks * 4 + lg) * 128) + n0w + lr) * 8;
      const bfrag bb0 = *reinterpret_cast<const bfrag*>(wp);
      const bfrag bb1 = *reinterpret_cast<const bfrag*>(wp + 16 * 8);
      acc[0][0] = __builtin_amdgcn_mfma_f32_16x16x32_bf16(a0, bb0, acc[0][0], 0, 0, 0);
      acc[1][0] = __builtin_amdgcn_mfma_f32_16x16x32_bf16(a1, bb0, acc[1][0], 0, 0, 0);
      acc[0][1] = __builtin_amdgcn_mfma_f32_16x16x32_bf16(a0, bb1, acc[0][1], 0, 0, 0);
      acc[1][1] = __builtin_amdgcn_mfma_f32_16x16x32_bf16(a1, bb1, acc[1][1], 0, 0, 0);
    }
    #pragma unroll
    for (int mt = 0; mt < 2; ++mt)
      #pragma unroll
      for (int nt = 0; nt < 2; ++nt)
        #pragma unroll
        for (int r = 0; r < 4; ++r)
          a2b[mt * 16 + lg * 4 + r][DD + n0w + nt * 16 + lr] = f2bf(fmaxf(acc[mt][nt][r], 0.f));
  }
  __syncthreads();  // a2b (prev|h) ready

  // ---- GEMM2: out = a2b @ W2 + b2 ----
  {
    const short* w2T = wT + W1T_SH;
    f32x4 acc[2][2];
    #pragma unroll
    for (int nt = 0; nt < 2; ++nt) {
      const float bv = b2g[n0w + nt * 16 + lr];
      acc[0][nt] = (f32x4){bv, bv, bv, bv};
      acc[1][nt] = (f32x4){bv, bv, bv, bv};
    }
    #pragma unroll
    for (int ks = 0; ks < 8; ++ks) {
      const bfrag a0 = *reinterpret_cast<const bfrag*>(&a2b[lr][ks * 32 + lg * 8]);
      const bfrag a1 = *reinterpret_cast<const bfrag*>(&a2b[16 + lr][ks * 32 + lg * 8]);
      const short* wp = w2T + ((size_t)((ks * 4 + lg) * 128) + n0w + lr) * 8;
      const bfrag bb0 = *reinterpret_cast<const bfrag*>(wp);
      const bfrag bb1 = *reinterpret_cast<const bfrag*>(wp + 16 * 8);
      acc[0][0] = __builtin_amdgcn_mfma_f32_16x16x32_bf16(a0, bb0, acc[0][0], 0, 0, 0);
      acc[1][0] = __builtin_amdgcn_mfma_f32_16x16x32_bf16(a1, bb0, acc[1][0], 0, 0, 0);
      acc[0][1] = __builtin_amdgcn_mfma_f32_16x16x32_bf16(a0, bb1, acc[0][1], 0, 0, 0);
      acc[1][1] = __builtin_amdgcn_mfma_f32_16x16x32_bf16(a1, bb1, acc[1][1], 0, 0, 0);
    }
    #pragma unroll
    for (int mt = 0; mt < 2; ++mt)
      #pragma unroll
      for (int nt = 0; nt < 2; ++nt)
        #pragma unroll
        for (int r = 0; r < 4; ++r) {
          const float v = acc[mt][nt][r];
          const size_t grow = (size_t)(n0 + mt * 16 + lg * 4 + r);
          const int    gcol = n0w + nt * 16 + lr;
          if constexpr (OUTBF) {
            ((short*)out_)[grow * DD + gcol] = f2bf(v);
          } else {
            __builtin_nontemporal_store(v, (float*)out_ + grow * DD + gcol);
          }
        }
  }
}

extern "C" void kernel_launch(void* const* d_in, const int* in_sizes, int n_in,
                              void* d_out, int out_size, void* d_ws, size_t ws_size,
                              hipStream_t stream) {
  const float* features = (const float*)d_in[0];
  const float* edge     = (const float*)d_in[1];
  const float* timef    = (const float*)d_in[2];
  const float* W1       = (const float*)d_in[3];
  const float* b1       = (const float*)d_in[4];
  const float* W2       = (const float*)d_in[5];
  const float* b2       = (const float*)d_in[6];
  const int*   idx      = (const int*)d_in[7];
  float* outp = (float*)d_out;

  short* wT     = (short*)d_ws;
  short* tmp    = (short*)((char*)d_ws + TMP_OFF_B);
  short* featbf = (short*)((char*)d_ws + FBF_OFF_B);

  dim3 block(256);

  prep_all<<<dim3(FBF_BLOCKS + PREP_BLOCKS), block, 0, stream>>>(
      features, featbf, W1, W2, wT);

  // layer 0: featbf -> tmp (bf16)
  tgn<true><<<dim3(GRID), block, 0, stream>>>(
      featbf, edge, timef, wT, b1, b2, idx, tmp);

  // layer 1: tmp -> out (f32)
  tgn<false><<<dim3(GRID), block, 0, stream>>>(
      tmp,
      edge  + (size_t)NN * KK * DEE,
      timef + (size_t)NN * KK * DTT,
      wT + WLAYER_SH,
      b1 + DD,
      b2 + DD,
      idx + (size_t)NN * KK,
      outp);
}

// Round 11
// 261.484 us; speedup vs baseline: 1.0551x; 1.0551x over previous
//
#include <hip/hip_runtime.h>

#define NN 100000
#define KK 16
#define DD 128
#define DEE 32
#define DTT 32
#define C1 192        // D + DE + DT
#define BN 32         // nodes per block
#define AB 200        // aggb row stride in shorts; ≡4 words mod 32 banks -> 2-way (free)
#define A2B 264       // a2b row stride in shorts; ≡4 words mod 32 banks -> 2-way (free)
#define GRID (NN / BN)

// ws layout
#define W1T_SH 24576                     // per layer: 24*128*8
#define WLAYER_SH 57344                  // shorts per layer (W1T + W2T)
#define WTOT_SH (2 * WLAYER_SH)          // 229376 B total
#define TMP_OFF_B 229376                 // bf16 layer-0 out
#define TMP_B (NN * DD * 2)              // 25.6 MB
#define FBF_OFF_B (TMP_OFF_B + TMP_B)    // bf16 features
#define FBF_B (NN * DD * 2)              // 25.6 MB

#define FBF_BLOCKS (NN * DD / 4 / 256)   // 12500
#define PREP_BLOCKS (WTOT_SH / 256)      // 448

typedef __attribute__((ext_vector_type(8))) short bfrag;    // 8 bf16 = 4 VGPR (MFMA A/B)
typedef __attribute__((ext_vector_type(4))) float f32x4;    // MFMA C/D + NT-loadable vec4
typedef __attribute__((ext_vector_type(4))) short short4v;  // 8-byte chunk

__device__ __forceinline__ short f2bf(float x) {  // RNE f32 -> bf16 bits
  unsigned u = __builtin_bit_cast(unsigned, x);
  unsigned r = u + 0x7fffu + ((u >> 16) & 1u);
  return (short)(r >> 16);
}
__device__ __forceinline__ float bf2f(short s) {
  unsigned u = ((unsigned)(unsigned short)s) << 16;
  return __builtin_bit_cast(float, u);
}

// ---- merged prep: features f32->bf16 table, then W1/W2 -> bf16 fragment-major ----
__global__ void prep_all(const float* __restrict__ f, short* __restrict__ fo,
                         const float* __restrict__ W1, const float* __restrict__ W2,
                         short* __restrict__ wo) {
  const int b = blockIdx.x;
  if (b < FBF_BLOCKS) {
    const size_t i = ((size_t)b * 256 + threadIdx.x) * 4;
    const f32x4 v = __builtin_nontemporal_load(reinterpret_cast<const f32x4*>(f + i));
    short4v s; s[0] = f2bf(v[0]); s[1] = f2bf(v[1]); s[2] = f2bf(v[2]); s[3] = f2bf(v[3]);
    *reinterpret_cast<short4v*>(fo + i) = s;
    return;
  }
  const int t = (b - FBF_BLOCKS) * 256 + threadIdx.x;
  const int l = t / WLAYER_SH;
  const int r = t % WLAYER_SH;
  float v;
  if (r < W1T_SH) {
    const int kg = r >> 10, col = (r >> 3) & 127, j = r & 7;
    v = W1[(size_t)l * C1 * DD + (size_t)(kg * 8 + j) * DD + col];
  } else {
    const int r2 = r - W1T_SH;
    const int kg = r2 >> 10, col = (r2 >> 3) & 127, j = r2 & 7;
    v = W2[(size_t)l * 2 * DD * DD + (size_t)(kg * 8 + j) * DD + col];
  }
  wo[t] = f2bf(v);
}

// ---- fused TGN layer (R9 structure + wave-parity phase staggering) ----
template<bool OUTBF>
__global__ __launch_bounds__(256, 5) void tgn(
    const short* __restrict__ prevb,  // bf16 gather table == GEMM2-A rows
    const float* __restrict__ edge,   // [N, K, DE]
    const float* __restrict__ timef,  // [N, K, DT]
    const short* __restrict__ wT,     // [W1T | W2T] bf16 fragment-major
    const float* __restrict__ b1g,    // [128]
    const float* __restrict__ b2g,    // [128]
    const int* __restrict__ idxg,     // [N, K]
    void* __restrict__ out_)          // [N, D]
{
  __shared__ short aggb[BN][AB];   // [nbr_sum | e_sum | t_sum], K=192
  __shared__ short a2b[BN][A2B];   // [prev | h], K=256

  const int t  = threadIdx.x;
  const int n0 = blockIdx.x * BN;   // NN % BN == 0

  // phase 0a: stage this block's own prev rows -> a2b[:, 0:128]
  {
    const int d4 = (t & 31) * 4;
    for (int nl = t >> 5; nl < BN; nl += 8) {
      const short4v o = *reinterpret_cast<const short4v*>(prevb + (size_t)(n0 + nl) * DD + d4);
      *reinterpret_cast<short4v*>(&a2b[nl][d4]) = o;
    }
  }

  // phase 0b: edge/time sums (HBM, NT stream) -> aggb[:, 128:192]
  auto do_stream = [&]() {
    const int c4 = (t & 7) * 4;
    const int nl = t >> 3;  // 0..31
    const f32x4* ep = reinterpret_cast<const f32x4*>(edge  + (size_t)(n0 + nl) * KK * DEE + c4);
    const f32x4* tp = reinterpret_cast<const f32x4*>(timef + (size_t)(n0 + nl) * KK * DTT + c4);
    float e0=0,e1=0,e2=0,e3=0, s0=0,s1=0,s2=0,s3=0;
    #pragma unroll
    for (int j = 0; j < KK; ++j) {
      const f32x4 ev = __builtin_nontemporal_load(ep + j * (DEE / 4));
      const f32x4 tv = __builtin_nontemporal_load(tp + j * (DTT / 4));
      e0 += ev[0]; e1 += ev[1]; e2 += ev[2]; e3 += ev[3];
      s0 += tv[0]; s1 += tv[1]; s2 += tv[2]; s3 += tv[3];
    }
    short4v eo; eo[0]=f2bf(e0); eo[1]=f2bf(e1); eo[2]=f2bf(e2); eo[3]=f2bf(e3);
    short4v so; so[0]=f2bf(s0); so[1]=f2bf(s1); so[2]=f2bf(s2); so[3]=f2bf(s3);
    *reinterpret_cast<short4v*>(&aggb[nl][DD + c4])       = eo;
    *reinterpret_cast<short4v*>(&aggb[nl][DD + DEE + c4]) = so;
  };

  // phase 0c: neighbor gather-sum (L3), two rows in flight -> aggb[:, 0:128]
  auto do_gather = [&]() {
    const int d4 = (t & 31) * 4;
    const int nr = t >> 5;  // 0..7
    #pragma unroll
    for (int p = 0; p < 2; ++p) {
      const int nlA = nr + p * 16;
      const int nlB = nlA + 8;
      const int4* ipA = reinterpret_cast<const int4*>(idxg + (size_t)(n0 + nlA) * KK);
      const int4* ipB = reinterpret_cast<const int4*>(idxg + (size_t)(n0 + nlB) * KK);
      const int4 a0i = ipA[0], a1i = ipA[1], a2i = ipA[2], a3i = ipA[3];
      const int4 b0i = ipB[0], b1i = ipB[1], b2i = ipB[2], b3i = ipB[3];
      const int rowsA[16] = {a0i.x, a0i.y, a0i.z, a0i.w, a1i.x, a1i.y, a1i.z, a1i.w,
                             a2i.x, a2i.y, a2i.z, a2i.w, a3i.x, a3i.y, a3i.z, a3i.w};
      const int rowsB[16] = {b0i.x, b0i.y, b0i.z, b0i.w, b1i.x, b1i.y, b1i.z, b1i.w,
                             b2i.x, b2i.y, b2i.z, b2i.w, b3i.x, b3i.y, b3i.z, b3i.w};
      float aA0=0, aA1=0, aA2=0, aA3=0;
      float aB0=0, aB1=0, aB2=0, aB3=0;
      #pragma unroll
      for (int j = 0; j < 16; ++j) {
        const short4v vA = *reinterpret_cast<const short4v*>(prevb + (size_t)rowsA[j] * DD + d4);
        const short4v vB = *reinterpret_cast<const short4v*>(prevb + (size_t)rowsB[j] * DD + d4);
        aA0 += bf2f(vA[0]); aA1 += bf2f(vA[1]); aA2 += bf2f(vA[2]); aA3 += bf2f(vA[3]);
        aB0 += bf2f(vB[0]); aB1 += bf2f(vB[1]); aB2 += bf2f(vB[2]); aB3 += bf2f(vB[3]);
      }
      short4v oA; oA[0]=f2bf(aA0); oA[1]=f2bf(aA1); oA[2]=f2bf(aA2); oA[3]=f2bf(aA3);
      short4v oB; oB[0]=f2bf(aB0); oB[1]=f2bf(aB1); oB[2]=f2bf(aB2); oB[3]=f2bf(aB3);
      *reinterpret_cast<short4v*>(&aggb[nlA][d4]) = oA;
      *reinterpret_cast<short4v*>(&aggb[nlB][d4]) = oB;
    }
  };

  // wave-parity stagger: even waves stream first, odd waves gather first.
  // Wave-uniform branch (t>>6 uniform per wave) -> no divergence; at any
  // instant ~half the CU's waves issue HBM, half issue L3.
  if ((t >> 6) & 1) { do_gather(); do_stream(); }
  else              { do_stream(); do_gather(); }

  __syncthreads();  // aggb + a2b[:,0:128] ready

  const int lane = t & 63;
  const int wv   = t >> 6;
  const int lr   = lane & 15;
  const int lg   = lane >> 4;
  const int n0w  = wv * 32;

  // ---- GEMM1: h = relu(aggb @ W1 + b1) -> a2b[:, 128:256] ----
  {
    f32x4 acc[2][2];
    #pragma unroll
    for (int nt = 0; nt < 2; ++nt) {
      const float bv = b1g[n0w + nt * 16 + lr];
      acc[0][nt] = (f32x4){bv, bv, bv, bv};
      acc[1][nt] = (f32x4){bv, bv, bv, bv};
    }
    #pragma unroll
    for (int ks = 0; ks < 6; ++ks) {
      const bfrag a0 = *reinterpret_cast<const bfrag*>(&aggb[lr][ks * 32 + lg * 8]);
      const bfrag a1 = *reinterpret_cast<const bfrag*>(&aggb[16 + lr][ks * 32 + lg * 8]);
      const short* wp = wT + ((size_t)((ks * 4 + lg) * 128) + n0w + lr) * 8;
      const bfrag bb0 = *reinterpret_cast<const bfrag*>(wp);
      const bfrag bb1 = *reinterpret_cast<const bfrag*>(wp + 16 * 8);
      acc[0][0] = __builtin_amdgcn_mfma_f32_16x16x32_bf16(a0, bb0, acc[0][0], 0, 0, 0);
      acc[1][0] = __builtin_amdgcn_mfma_f32_16x16x32_bf16(a1, bb0, acc[1][0], 0, 0, 0);
      acc[0][1] = __builtin_amdgcn_mfma_f32_16x16x32_bf16(a0, bb1, acc[0][1], 0, 0, 0);
      acc[1][1] = __builtin_amdgcn_mfma_f32_16x16x32_bf16(a1, bb1, acc[1][1], 0, 0, 0);
    }
    #pragma unroll
    for (int mt = 0; mt < 2; ++mt)
      #pragma unroll
      for (int nt = 0; nt < 2; ++nt)
        #pragma unroll
        for (int r = 0; r < 4; ++r)
          a2b[mt * 16 + lg * 4 + r][DD + n0w + nt * 16 + lr] = f2bf(fmaxf(acc[mt][nt][r], 0.f));
  }
  __syncthreads();  // a2b (prev|h) ready

  // ---- GEMM2: out = a2b @ W2 + b2 ----
  {
    const short* w2T = wT + W1T_SH;
    f32x4 acc[2][2];
    #pragma unroll
    for (int nt = 0; nt < 2; ++nt) {
      const float bv = b2g[n0w + nt * 16 + lr];
      acc[0][nt] = (f32x4){bv, bv, bv, bv};
      acc[1][nt] = (f32x4){bv, bv, bv, bv};
    }
    #pragma unroll
    for (int ks = 0; ks < 8; ++ks) {
      const bfrag a0 = *reinterpret_cast<const bfrag*>(&a2b[lr][ks * 32 + lg * 8]);
      const bfrag a1 = *reinterpret_cast<const bfrag*>(&a2b[16 + lr][ks * 32 + lg * 8]);
      const short* wp = w2T + ((size_t)((ks * 4 + lg) * 128) + n0w + lr) * 8;
      const bfrag bb0 = *reinterpret_cast<const bfrag*>(wp);
      const bfrag bb1 = *reinterpret_cast<const bfrag*>(wp + 16 * 8);
      acc[0][0] = __builtin_amdgcn_mfma_f32_16x16x32_bf16(a0, bb0, acc[0][0], 0, 0, 0);
      acc[1][0] = __builtin_amdgcn_mfma_f32_16x16x32_bf16(a1, bb0, acc[1][0], 0, 0, 0);
      acc[0][1] = __builtin_amdgcn_mfma_f32_16x16x32_bf16(a0, bb1, acc[0][1], 0, 0, 0);
      acc[1][1] = __builtin_amdgcn_mfma_f32_16x16x32_bf16(a1, bb1, acc[1][1], 0, 0, 0);
    }
    #pragma unroll
    for (int mt = 0; mt < 2; ++mt)
      #pragma unroll
      for (int nt = 0; nt < 2; ++nt)
        #pragma unroll
        for (int r = 0; r < 4; ++r) {
          const float v = acc[mt][nt][r];
          const size_t grow = (size_t)(n0 + mt * 16 + lg * 4 + r);
          const int    gcol = n0w + nt * 16 + lr;
          if constexpr (OUTBF) {
            ((short*)out_)[grow * DD + gcol] = f2bf(v);
          } else {
            __builtin_nontemporal_store(v, (float*)out_ + grow * DD + gcol);
          }
        }
  }
}

extern "C" void kernel_launch(void* const* d_in, const int* in_sizes, int n_in,
                              void* d_out, int out_size, void* d_ws, size_t ws_size,
                              hipStream_t stream) {
  const float* features = (const float*)d_in[0];
  const float* edge     = (const float*)d_in[1];
  const float* timef    = (const float*)d_in[2];
  const float* W1       = (const float*)d_in[3];
  const float* b1       = (const float*)d_in[4];
  const float* W2       = (const float*)d_in[5];
  const float* b2       = (const float*)d_in[6];
  const int*   idx      = (const int*)d_in[7];
  float* outp = (float*)d_out;

  short* wT     = (short*)d_ws;
  short* tmp    = (short*)((char*)d_ws + TMP_OFF_B);
  short* featbf = (short*)((char*)d_ws + FBF_OFF_B);

  dim3 block(256);

  prep_all<<<dim3(FBF_BLOCKS + PREP_BLOCKS), block, 0, stream>>>(
      features, featbf, W1, W2, wT);

  // layer 0: featbf -> tmp (bf16)
  tgn<true><<<dim3(GRID), block, 0, stream>>>(
      featbf, edge, timef, wT, b1, b2, idx, tmp);

  // layer 1: tmp -> out (f32)
  tgn<false><<<dim3(GRID), block, 0, stream>>>(
      tmp,
      edge  + (size_t)NN * KK * DEE,
      timef + (size_t)NN * KK * DTT,
      wT + WLAYER_SH,
      b1 + DD,
      b2 + DD,
      idx + (size_t)NN * KK,
      outp);
}

// Round 12
// 259.935 us; speedup vs baseline: 1.0614x; 1.0060x over previous
//
#include <hip/hip_runtime.h>

#define NN 100000
#define KK 16
#define DD 128
#define DEE 32
#define DTT 32
#define C1 192        // D + DE + DT
#define BN 32         // nodes per block
#define AB 200        // aggb row stride in shorts; ≡4 words mod 32 banks -> 2-way (free)
#define A2B 264       // a2b row stride in shorts; ≡4 words mod 32 banks -> 2-way (free)
#define GRID (NN / BN)

// ws layout
#define W1T_SH 24576                     // per layer: 24*128*8
#define WLAYER_SH 57344                  // shorts per layer (W1T + W2T)
#define WTOT_SH (2 * WLAYER_SH)          // 229376 B total
#define TMP_OFF_B 229376                 // bf16 layer-0 out
#define TMP_B (NN * DD * 2)              // 25.6 MB
#define FBF_OFF_B (TMP_OFF_B + TMP_B)    // bf16 features
#define FBF_B (NN * DD * 2)              // 25.6 MB

#define FBF_BLOCKS (NN * DD / 4 / 256)   // 12500
#define PREP_BLOCKS (WTOT_SH / 256)      // 448

typedef __attribute__((ext_vector_type(8))) short bfrag;    // 8 bf16 = 4 VGPR (MFMA A/B)
typedef __attribute__((ext_vector_type(4))) float f32x4;    // MFMA C/D + NT-loadable vec4
typedef __attribute__((ext_vector_type(4))) short short4v;  // 8-byte chunk

__device__ __forceinline__ short f2bf(float x) {  // RNE f32 -> bf16 bits
  unsigned u = __builtin_bit_cast(unsigned, x);
  unsigned r = u + 0x7fffu + ((u >> 16) & 1u);
  return (short)(r >> 16);
}
__device__ __forceinline__ float bf2f(short s) {
  unsigned u = ((unsigned)(unsigned short)s) << 16;
  return __builtin_bit_cast(float, u);
}

// ---- merged prep: features f32->bf16 table, then W1/W2 -> bf16 fragment-major ----
__global__ void prep_all(const float* __restrict__ f, short* __restrict__ fo,
                         const float* __restrict__ W1, const float* __restrict__ W2,
                         short* __restrict__ wo) {
  const int b = blockIdx.x;
  if (b < FBF_BLOCKS) {
    const size_t i = ((size_t)b * 256 + threadIdx.x) * 4;
    const f32x4 v = __builtin_nontemporal_load(reinterpret_cast<const f32x4*>(f + i));
    short4v s; s[0] = f2bf(v[0]); s[1] = f2bf(v[1]); s[2] = f2bf(v[2]); s[3] = f2bf(v[3]);
    *reinterpret_cast<short4v*>(fo + i) = s;
    return;
  }
  const int t = (b - FBF_BLOCKS) * 256 + threadIdx.x;
  const int l = t / WLAYER_SH;
  const int r = t % WLAYER_SH;
  float v;
  if (r < W1T_SH) {
    const int kg = r >> 10, col = (r >> 3) & 127, j = r & 7;
    v = W1[(size_t)l * C1 * DD + (size_t)(kg * 8 + j) * DD + col];
  } else {
    const int r2 = r - W1T_SH;
    const int kg = r2 >> 10, col = (r2 >> 3) & 127, j = r2 & 7;
    v = W2[(size_t)l * 2 * DD * DD + (size_t)(kg * 8 + j) * DD + col];
  }
  wo[t] = f2bf(v);
}

// ---- fused TGN layer (R9-proven structure: NT streams + dual-row gather) ----
template<bool OUTBF>
__global__ __launch_bounds__(256, 5) void tgn(
    const short* __restrict__ prevb,  // bf16 gather table == GEMM2-A rows
    const float* __restrict__ edge,   // [N, K, DE]
    const float* __restrict__ timef,  // [N, K, DT]
    const short* __restrict__ wT,     // [W1T | W2T] bf16 fragment-major
    const float* __restrict__ b1g,    // [128]
    const float* __restrict__ b2g,    // [128]
    const int* __restrict__ idxg,     // [N, K]
    void* __restrict__ out_)          // [N, D]
{
  __shared__ short aggb[BN][AB];   // [nbr_sum | e_sum | t_sum], K=192
  __shared__ short a2b[BN][A2B];   // [prev | h], K=256

  const int t  = threadIdx.x;
  const int n0 = blockIdx.x * BN;   // NN % BN == 0

  // phase 0a: stage this block's own prev rows -> a2b[:, 0:128]
  {
    const int d4 = (t & 31) * 4;
    for (int nl = t >> 5; nl < BN; nl += 8) {
      const short4v o = *reinterpret_cast<const short4v*>(prevb + (size_t)(n0 + nl) * DD + d4);
      *reinterpret_cast<short4v*>(&a2b[nl][d4]) = o;
    }
  }

  // phase 0b: edge/time sums -> aggb[:, 128:192]  (non-temporal: read-once stream)
  {
    const int c4 = (t & 7) * 4;
    const int nl = t >> 3;  // 0..31
    const f32x4* ep = reinterpret_cast<const f32x4*>(edge  + (size_t)(n0 + nl) * KK * DEE + c4);
    const f32x4* tp = reinterpret_cast<const f32x4*>(timef + (size_t)(n0 + nl) * KK * DTT + c4);
    float e0=0,e1=0,e2=0,e3=0, s0=0,s1=0,s2=0,s3=0;
    #pragma unroll
    for (int j = 0; j < KK; ++j) {
      const f32x4 ev = __builtin_nontemporal_load(ep + j * (DEE / 4));
      const f32x4 tv = __builtin_nontemporal_load(tp + j * (DTT / 4));
      e0 += ev[0]; e1 += ev[1]; e2 += ev[2]; e3 += ev[3];
      s0 += tv[0]; s1 += tv[1]; s2 += tv[2]; s3 += tv[3];
    }
    short4v eo; eo[0]=f2bf(e0); eo[1]=f2bf(e1); eo[2]=f2bf(e2); eo[3]=f2bf(e3);
    short4v so; so[0]=f2bf(s0); so[1]=f2bf(s1); so[2]=f2bf(s2); so[3]=f2bf(s3);
    *reinterpret_cast<short4v*>(&aggb[nl][DD + c4])       = eo;
    *reinterpret_cast<short4v*>(&aggb[nl][DD + DEE + c4]) = so;
  }

  // phase 0c: neighbor gather-sum, two rows in flight per thread -> aggb[:, 0:128]
  {
    const int d4 = (t & 31) * 4;
    const int nr = t >> 5;  // 0..7
    #pragma unroll
    for (int p = 0; p < 2; ++p) {
      const int nlA = nr + p * 16;
      const int nlB = nlA + 8;
      const int4* ipA = reinterpret_cast<const int4*>(idxg + (size_t)(n0 + nlA) * KK);
      const int4* ipB = reinterpret_cast<const int4*>(idxg + (size_t)(n0 + nlB) * KK);
      const int4 a0i = ipA[0], a1i = ipA[1], a2i = ipA[2], a3i = ipA[3];
      const int4 b0i = ipB[0], b1i = ipB[1], b2i = ipB[2], b3i = ipB[3];
      const int rowsA[16] = {a0i.x, a0i.y, a0i.z, a0i.w, a1i.x, a1i.y, a1i.z, a1i.w,
                             a2i.x, a2i.y, a2i.z, a2i.w, a3i.x, a3i.y, a3i.z, a3i.w};
      const int rowsB[16] = {b0i.x, b0i.y, b0i.z, b0i.w, b1i.x, b1i.y, b1i.z, b1i.w,
                             b2i.x, b2i.y, b2i.z, b2i.w, b3i.x, b3i.y, b3i.z, b3i.w};
      float aA0=0, aA1=0, aA2=0, aA3=0;
      float aB0=0, aB1=0, aB2=0, aB3=0;
      #pragma unroll
      for (int j = 0; j < 16; ++j) {
        const short4v vA = *reinterpret_cast<const short4v*>(prevb + (size_t)rowsA[j] * DD + d4);
        const short4v vB = *reinterpret_cast<const short4v*>(prevb + (size_t)rowsB[j] * DD + d4);
        aA0 += bf2f(vA[0]); aA1 += bf2f(vA[1]); aA2 += bf2f(vA[2]); aA3 += bf2f(vA[3]);
        aB0 += bf2f(vB[0]); aB1 += bf2f(vB[1]); aB2 += bf2f(vB[2]); aB3 += bf2f(vB[3]);
      }
      short4v oA; oA[0]=f2bf(aA0); oA[1]=f2bf(aA1); oA[2]=f2bf(aA2); oA[3]=f2bf(aA3);
      short4v oB; oB[0]=f2bf(aB0); oB[1]=f2bf(aB1); oB[2]=f2bf(aB2); oB[3]=f2bf(aB3);
      *reinterpret_cast<short4v*>(&aggb[nlA][d4]) = oA;
      *reinterpret_cast<short4v*>(&aggb[nlB][d4]) = oB;
    }
  }
  __syncthreads();  // aggb + a2b[:,0:128] ready

  const int lane = t & 63;
  const int wv   = t >> 6;
  const int lr   = lane & 15;
  const int lg   = lane >> 4;
  const int n0w  = wv * 32;

  // ---- GEMM1: h = relu(aggb @ W1 + b1) -> a2b[:, 128:256] ----
  {
    f32x4 acc[2][2];
    #pragma unroll
    for (int nt = 0; nt < 2; ++nt) {
      const float bv = b1g[n0w + nt * 16 + lr];
      acc[0][nt] = (f32x4){bv, bv, bv, bv};
      acc[1][nt] = (f32x4){bv, bv, bv, bv};
    }
    #pragma unroll
    for (int ks = 0; ks < 6; ++ks) {
      const bfrag a0 = *reinterpret_cast<const bfrag*>(&aggb[lr][ks * 32 + lg * 8]);
      const bfrag a1 = *reinterpret_cast<const bfrag*>(&aggb[16 + lr][ks * 32 + lg * 8]);
      const short* wp = wT + ((size_t)((ks * 4 + lg) * 128) + n0w + lr) * 8;
      const bfrag bb0 = *reinterpret_cast<const bfrag*>(wp);
      const bfrag bb1 = *reinterpret_cast<const bfrag*>(wp + 16 * 8);
      acc[0][0] = __builtin_amdgcn_mfma_f32_16x16x32_bf16(a0, bb0, acc[0][0], 0, 0, 0);
      acc[1][0] = __builtin_amdgcn_mfma_f32_16x16x32_bf16(a1, bb0, acc[1][0], 0, 0, 0);
      acc[0][1] = __builtin_amdgcn_mfma_f32_16x16x32_bf16(a0, bb1, acc[0][1], 0, 0, 0);
      acc[1][1] = __builtin_amdgcn_mfma_f32_16x16x32_bf16(a1, bb1, acc[1][1], 0, 0, 0);
    }
    #pragma unroll
    for (int mt = 0; mt < 2; ++mt)
      #pragma unroll
      for (int nt = 0; nt < 2; ++nt)
        #pragma unroll
        for (int r = 0; r < 4; ++r)
          a2b[mt * 16 + lg * 4 + r][DD + n0w + nt * 16 + lr] = f2bf(fmaxf(acc[mt][nt][r], 0.f));
  }
  __syncthreads();  // a2b (prev|h) ready

  // ---- GEMM2: out = a2b @ W2 + b2 ----
  {
    const short* w2T = wT + W1T_SH;
    f32x4 acc[2][2];
    #pragma unroll
    for (int nt = 0; nt < 2; ++nt) {
      const float bv = b2g[n0w + nt * 16 + lr];
      acc[0][nt] = (f32x4){bv, bv, bv, bv};
      acc[1][nt] = (f32x4){bv, bv, bv, bv};
    }
    #pragma unroll
    for (int ks = 0; ks < 8; ++ks) {
      const bfrag a0 = *reinterpret_cast<const bfrag*>(&a2b[lr][ks * 32 + lg * 8]);
      const bfrag a1 = *reinterpret_cast<const bfrag*>(&a2b[16 + lr][ks * 32 + lg * 8]);
      const short* wp = w2T + ((size_t)((ks * 4 + lg) * 128) + n0w + lr) * 8;
      const bfrag bb0 = *reinterpret_cast<const bfrag*>(wp);
      const bfrag bb1 = *reinterpret_cast<const bfrag*>(wp + 16 * 8);
      acc[0][0] = __builtin_amdgcn_mfma_f32_16x16x32_bf16(a0, bb0, acc[0][0], 0, 0, 0);
      acc[1][0] = __builtin_amdgcn_mfma_f32_16x16x32_bf16(a1, bb0, acc[1][0], 0, 0, 0);
      acc[0][1] = __builtin_amdgcn_mfma_f32_16x16x32_bf16(a0, bb1, acc[0][1], 0, 0, 0);
      acc[1][1] = __builtin_amdgcn_mfma_f32_16x16x32_bf16(a1, bb1, acc[1][1], 0, 0, 0);
    }
    #pragma unroll
    for (int mt = 0; mt < 2; ++mt)
      #pragma unroll
      for (int nt = 0; nt < 2; ++nt)
        #pragma unroll
        for (int r = 0; r < 4; ++r) {
          const float v = acc[mt][nt][r];
          const size_t grow = (size_t)(n0 + mt * 16 + lg * 4 + r);
          const int    gcol = n0w + nt * 16 + lr;
          if constexpr (OUTBF) {
            ((short*)out_)[grow * DD + gcol] = f2bf(v);
          } else {
            __builtin_nontemporal_store(v, (float*)out_ + grow * DD + gcol);
          }
        }
  }
}

extern "C" void kernel_launch(void* const* d_in, const int* in_sizes, int n_in,
                              void* d_out, int out_size, void* d_ws, size_t ws_size,
                              hipStream_t stream) {
  const float* features = (const float*)d_in[0];
  const float* edge     = (const float*)d_in[1];
  const float* timef    = (const float*)d_in[2];
  const float* W1       = (const float*)d_in[3];
  const float* b1       = (const float*)d_in[4];
  const float* W2       = (const float*)d_in[5];
  const float* b2       = (const float*)d_in[6];
  const int*   idx      = (const int*)d_in[7];
  float* outp = (float*)d_out;

  short* wT     = (short*)d_ws;
  short* tmp    = (short*)((char*)d_ws + TMP_OFF_B);
  short* featbf = (short*)((char*)d_ws + FBF_OFF_B);

  dim3 block(256);

  prep_all<<<dim3(FBF_BLOCKS + PREP_BLOCKS), block, 0, stream>>>(
      features, featbf, W1, W2, wT);

  // layer 0: featbf -> tmp (bf16)
  tgn<true><<<dim3(GRID), block, 0, stream>>>(
      featbf, edge, timef, wT, b1, b2, idx, tmp);

  // layer 1: tmp -> out (f32)
  tgn<false><<<dim3(GRID), block, 0, stream>>>(
      tmp,
      edge  + (size_t)NN * KK * DEE,
      timef + (size_t)NN * KK * DTT,
      wT + WLAYER_SH,
      b1 + DD,
      b2 + DD,
      idx + (size_t)NN * KK,
      outp);
}